// Round 9
// baseline (444.231 us; speedup 1.0000x reference)
//
#include <hip/hip_runtime.h>
#include <hip/hip_bf16.h>
#include <math.h>

// ---------------------------------------------------------------------------
// EncoderLayer, bf16-MFMA mixed precision for MI355X (gfx950).
// B=8, S=2048, D=512, H=8, DK=64, DFF=2048, M=16384.
// All GEMMs + attention matmuls: mfma_f32_16x16x32_bf16 (fp32 accumulate).
// Softmax (exp2 domain), LayerNorm, residuals, bias: fp32.
// Round-9 changes:
//  * attn: K fragments loaded global->registers directly (K panel is
//    XCD-L2-resident via the r7 swizzle) -- removes ~30% of attn DS traffic.
//  * QKV/FFN1 GEMMs: wave tile 64x128 (block 128x256, acc 4x8) -- fewer
//    DS reads, staging ops and barriers per FLOP. WO/FFN2 stay 4x4.
//  * pack_t: LDS-tiled transpose (coalesced both sides).
//  * LN1 writes bf16 only; FFN2 residual read in bf16.
// ---------------------------------------------------------------------------

#define D_MODEL 512
#define NHEAD   8
#define DKH     64
#define SEQ     2048
#define BATCH   8
#define DFF     2048
#define MROWS   (BATCH * SEQ)          // 16384
#define QKVLD   1536                   // fused q|k|v row stride

typedef __bf16 bf16x8 __attribute__((ext_vector_type(8)));
typedef float  f32x4  __attribute__((ext_vector_type(4)));

__device__ __forceinline__ unsigned short f2bf(float f) {
    union { float f; unsigned u; } v; v.f = f;
    return (unsigned short)((v.u + 0x7FFFu + ((v.u >> 16) & 1u)) >> 16);
}

__device__ __forceinline__ float bf2f(unsigned short u) {
    union { unsigned u; float f; } v; v.u = (unsigned)u << 16;
    return v.f;
}

__device__ __forceinline__ unsigned cvtpk(float a, float b) {   // bf16(a)|bf16(b)<<16, RNE
    unsigned r;
    asm("v_cvt_pk_bf16_f32 %0, %1, %2" : "=v"(r) : "v"(a), "v"(b));
    return r;
}

__device__ __forceinline__ float fexp2(float x) {   // raw v_exp_f32 (2^x)
    float r; asm("v_exp_f32 %0, %1" : "=v"(r) : "v"(x)); return r;
}

__device__ __forceinline__ f32x4 mfma16(bf16x8 a, bf16x8 b, f32x4 c) {
    return __builtin_amdgcn_mfma_f32_16x16x32_bf16(a, b, c, 0, 0, 0);
}

// async global -> LDS, 16 B per lane; lds base must be wave-uniform
__device__ __forceinline__ void gld_lds16(const unsigned short* g, unsigned short* l) {
    __builtin_amdgcn_global_load_lds(
        (const __attribute__((address_space(1))) unsigned int*)g,
        (__attribute__((address_space(3))) unsigned int*)l, 16, 0, 0);
}

// ---------------------------------------------------------------------------
// bf16 MFMA GEMM: C[M,N] = A[M,K] * Bt[N,K]^T  (+bias, +relu, +residual)
// NF=4: block 128x128, 4 waves of 64x64 (acc 4x4).
// NF=8: block 128x256, 4 waves of 64x128 (acc 4x8) -- fewer DS/staging ops
//       per FLOP for the wide-N GEMMs.
// Double-buffered global_load_lds staging (issue next tile before MFMAs).
// RESMODE: 0 none, 1 fp32, 2 bf16.
// ---------------------------------------------------------------------------
template<int NF, bool BIAS, bool RELU, int RESMODE, bool OUTF32>
__global__ __launch_bounds__(256)
void mfma_gemm(const unsigned short* __restrict__ Av,
               const unsigned short* __restrict__ Bt,
               const float* __restrict__ bias, const void* __restrict__ resv,
               void* __restrict__ Cv, int Kdim, int lda, int ldc)
{
    constexpr int BN = NF * 32;                  // block cols: 128 or 256
    __shared__ unsigned short As[2][128][32];
    __shared__ unsigned short Bs[2][BN][32];

    const int tid  = threadIdx.x;
    const int lane = tid & 63;
    const int w    = tid >> 6;
    const int mq   = (w >> 1) << 6;              // wave quadrant row
    const int nq   = (w & 1) * (NF * 16);        // wave quadrant col
    const int lrow = lane & 15;
    const int g    = lane >> 4;
    const int lk   = g << 3;                     // k offset of lane's 8 elems

    const int row0 = blockIdx.y << 7;
    const int col0 = blockIdx.x * BN;

    // staging: wave w covers A rows [w*32, w*32+32) and B rows
    // [w*(BN/4), ...+BN/4); lane slot: +(lane>>2) row, (lane&3)*8 col.
    const int c0a  = w << 5;
    const int c0b  = w * (BN / 4);
    const int srow = lane >> 2;
    const int scol = (lane & 3) << 3;
    const size_t aoff = (size_t)(row0 + c0a + srow) * lda  + scol;
    const size_t boff = (size_t)(col0 + c0b + srow) * Kdim + scol;

    auto stage = [&](int buf, int kt) {
        gld_lds16(Av + aoff + kt,                     &As[buf][c0a     ][0]);
        gld_lds16(Av + aoff + (size_t)16 * lda + kt,  &As[buf][c0a + 16][0]);
        #pragma unroll
        for (int j = 0; j < BN / 64; ++j)
            gld_lds16(Bt + boff + (size_t)(16 * j) * Kdim + kt,
                      &Bs[buf][c0b + 16 * j][0]);
    };

    const f32x4 zero = {0.f, 0.f, 0.f, 0.f};
    f32x4 acc[4][NF];
    #pragma unroll
    for (int i = 0; i < 4; ++i)
        #pragma unroll
        for (int j = 0; j < NF; ++j) acc[i][j] = zero;

    stage(0, 0);
    __syncthreads();           // drains vmcnt -> buf0 visible

    int cur = 0;
    for (int kt = 0; kt < Kdim; kt += 32) {
        if (kt + 32 < Kdim) stage(cur ^ 1, kt + 32);   // in flight over compute

        bf16x8 af[4];
        #pragma unroll
        for (int mf = 0; mf < 4; ++mf)
            af[mf] = *(const bf16x8*)&As[cur][mq + mf * 16 + lrow][lk];
        #pragma unroll
        for (int nf = 0; nf < NF; ++nf) {
            const bf16x8 bf = *(const bf16x8*)&Bs[cur][nq + nf * 16 + lrow][lk];
            #pragma unroll
            for (int mf = 0; mf < 4; ++mf)
                acc[mf][nf] = mfma16(af[mf], bf, acc[mf][nf]);
        }

        __syncthreads();       // drains vmcnt (next buf ready) + read fence
        cur ^= 1;
    }

    // epilogue: C/D layout col = lane&15, row = 4*(lane>>4)+reg
    const int orow = row0 + mq + g * 4;
    const int ocol = col0 + nq + lrow;
    #pragma unroll
    for (int mf = 0; mf < 4; ++mf) {
        #pragma unroll
        for (int nf = 0; nf < NF; ++nf) {
            const int cc = ocol + nf * 16;
            float bv = 0.f;
            if constexpr (BIAS) bv = bias[cc];
            float v[4];
            #pragma unroll
            for (int r = 0; r < 4; ++r) {
                const int rr = orow + mf * 16 + r;
                v[r] = acc[mf][nf][r];
                if constexpr (BIAS) v[r] += bv;
                if constexpr (RELU) v[r] = fmaxf(v[r], 0.f);
                if constexpr (RESMODE == 1)
                    v[r] += ((const float*)resv)[(size_t)rr * ldc + cc];
                if constexpr (RESMODE == 2)
                    v[r] += bf2f(((const unsigned short*)resv)[(size_t)rr * ldc + cc]);
                if constexpr (OUTF32) ((float*)Cv)[(size_t)rr * ldc + cc] = v[r];
            }
            if constexpr (!OUTF32) {
                const unsigned u01 = cvtpk(v[0], v[1]);
                const unsigned u23 = cvtpk(v[2], v[3]);
                unsigned short* cp = (unsigned short*)Cv + (size_t)(orow + mf * 16) * ldc + cc;
                cp[0]                 = (unsigned short)u01;
                cp[(size_t)ldc]       = (unsigned short)(u01 >> 16);
                cp[(size_t)ldc * 2]   = (unsigned short)u23;
                cp[(size_t)ldc * 3]   = (unsigned short)(u23 >> 16);
            }
        }
    }
}

// ---------------------------------------------------------------------------
// Flash attention v3: 8 waves x 32 Q-rows = 256 Q-rows/block, KV tiles of 64.
// K fragments loaded DIRECTLY global->registers (K panel is L2-resident via
// the XCD swizzle) -- no K in LDS. V staged in LDS (transpose needed), P in
// permuted-kv layout (ds_write_b64). Softmax exp2-domain, defer-max, lazy sum.
// ---------------------------------------------------------------------------
__device__ __forceinline__ void softmax_store(
    f32x4* sacc, float* mrun, float* lpart, f32x4* oacc,
    unsigned short (*Ps)[76], int rowbase, int g, int lrow)
{
    float pmax[4];
    bool need = false;
    #pragma unroll
    for (int r = 0; r < 4; ++r) {
        pmax[r] = fmaxf(fmaxf(sacc[0][r], sacc[1][r]),
                        fmaxf(sacc[2][r], sacc[3][r]));
        need |= (pmax[r] > mrun[r] + 8.f);
    }
    if (__any(need)) {   // rare after first tile: full max-reduce + rescale
        #pragma unroll
        for (int r = 0; r < 4; ++r) {
            float mt = pmax[r];
            mt = fmaxf(mt, __shfl_xor(mt, 1, 16));
            mt = fmaxf(mt, __shfl_xor(mt, 2, 16));
            mt = fmaxf(mt, __shfl_xor(mt, 4, 16));
            mt = fmaxf(mt, __shfl_xor(mt, 8, 16));
            const float mnew = fmaxf(mrun[r], mt);
            const float alpha = fexp2(mrun[r] - mnew);  // first tile: 0
            mrun[r] = mnew;
            lpart[r] *= alpha;
            #pragma unroll
            for (int nf = 0; nf < 4; ++nf) oacc[nf][r] *= alpha;
        }
    }
    #pragma unroll
    for (int r = 0; r < 4; ++r) {
        const float p0 = fexp2(sacc[0][r] - mrun[r]);
        const float p1 = fexp2(sacc[1][r] - mrun[r]);
        const float p2 = fexp2(sacc[2][r] - mrun[r]);
        const float p3 = fexp2(sacc[3][r] - mrun[r]);
        lpart[r] += (p0 + p1) + (p2 + p3);
        uint2 u;
        u.x = cvtpk(p0, p1);     // cols 4*lrow, 4*lrow+1  (nf=0,1)
        u.y = cvtpk(p2, p3);     // cols 4*lrow+2, +3      (nf=2,3)
        *(uint2*)&Ps[rowbase + g * 4 + r][4 * lrow] = u;
    }
}

__global__ __launch_bounds__(512, 4)
void mfma_attn(unsigned short* __restrict__ qkv)
{
    __shared__ unsigned short Vt[64][72];    // V' transposed [dk][c(kv)]
    __shared__ unsigned short Ps[256][76];   // P' [qrow][c(kv)]

    const int tid  = threadIdx.x;
    const int lane = tid & 63;
    const int w    = tid >> 6;
    const int lrow = lane & 15;
    const int g    = lane >> 4;
    const int lk   = g << 3;

    // XCD swizzle: 512 blocks = 8 xcd x 8 bh-groups x 8 q-tiles
    const int bid  = blockIdx.x;
    const int idx  = bid >> 3;
    const int bh   = (bid & 7) * 8 + (idx & 7);
    const int b  = bh >> 3, h = bh & 7;
    const int s0 = (idx >> 3) << 8;              // q-tile start (256 rows)

    unsigned short* qptr = qkv + ((size_t)(b * SEQ + s0)) * QKVLD + h * DKH;
    const unsigned short* kbase = qkv + ((size_t)(b * SEQ)) * QKVLD + 512 + h * DKH;
    const unsigned short* vbase = qkv + ((size_t)(b * SEQ)) * QKVLD + 1024 + h * DKH;

    // Q fragments for both 16-row sub-tiles (pre-scaled 0.125*log2e via pack)
    bf16x8 qf[2][2];
    #pragma unroll
    for (int sub = 0; sub < 2; ++sub) {
        const unsigned short* qp = qptr + (size_t)(w * 32 + sub * 16 + lrow) * QKVLD;
        qf[sub][0] = *(const bf16x8*)(qp + lk);
        qf[sub][1] = *(const bf16x8*)(qp + 32 + lk);
    }

    // V staging indices
    const int vr = tid & 63, vc = (tid >> 6) << 3;  // V: row=vr, 8-col slab
    const int cvr = ((vr & 15) << 2) | (vr >> 4);   // permuted col of kv=vr

    uint4 vreg;
    auto loadV = [&](int t0) {
        vreg = *(const uint4*)(vbase + (size_t)(t0 + vr) * QKVLD + vc);
    };
    loadV(0);

    const f32x4 zero = {0.f, 0.f, 0.f, 0.f};
    f32x4 oacc0[4], oacc1[4];
    float m0[4], l0[4], m1[4], l1[4];
    #pragma unroll
    for (int i = 0; i < 4; ++i) {
        oacc0[i] = zero; oacc1[i] = zero;
        m0[i] = -INFINITY; m1[i] = -INFINITY; l0[i] = 0.f; l1[i] = 0.f;
    }

    for (int t0 = 0; t0 < SEQ; t0 += 64) {
        // K fragments: global -> regs (L2-hit; issued early, consumed after
        // the two barriers + V staging below -> latency covered)
        bf16x8 kf[2][4];
        #pragma unroll
        for (int kk = 0; kk < 2; ++kk)
            #pragma unroll
            for (int nf = 0; nf < 4; ++nf)
                kf[kk][nf] = *(const bf16x8*)(
                    kbase + (size_t)(t0 + nf * 16 + lrow) * QKVLD + kk * 32 + lk);

        __syncthreads();   // previous tile's LDS reads complete
        {
            const unsigned short* vu = (const unsigned short*)&vreg;
            #pragma unroll
            for (int j = 0; j < 8; ++j) Vt[vc + j][cvr] = vu[j];
        }
        __syncthreads();

        if (t0 + 64 < SEQ) loadV(t0 + 64);   // prefetch next V tile

        // S = Q K^T for both sub-tiles (kf shared across sub-tiles)
        f32x4 s0a[4], s1a[4];
        #pragma unroll
        for (int nf = 0; nf < 4; ++nf) { s0a[nf] = zero; s1a[nf] = zero; }
        __builtin_amdgcn_s_setprio(1);
        #pragma unroll
        for (int kk = 0; kk < 2; ++kk) {
            #pragma unroll
            for (int nf = 0; nf < 4; ++nf) {
                s0a[nf] = mfma16(qf[0][kk], kf[kk][nf], s0a[nf]);
                s1a[nf] = mfma16(qf[1][kk], kf[kk][nf], s1a[nf]);
            }
        }
        __builtin_amdgcn_s_setprio(0);

        softmax_store(s0a, m0, l0, oacc0, Ps, w * 32,      g, lrow);
        softmax_store(s1a, m1, l1, oacc1, Ps, w * 32 + 16, g, lrow);

        // O += P' V'   (vf shared across sub-tiles)
        __builtin_amdgcn_s_setprio(1);
        #pragma unroll
        for (int kk = 0; kk < 2; ++kk) {
            const bf16x8 pf0 = *(const bf16x8*)&Ps[w * 32 + lrow][kk * 32 + lk];
            const bf16x8 pf1 = *(const bf16x8*)&Ps[w * 32 + 16 + lrow][kk * 32 + lk];
            #pragma unroll
            for (int nf = 0; nf < 4; ++nf) {
                const bf16x8 vf = *(const bf16x8*)&Vt[nf * 16 + lrow][kk * 32 + lk];
                oacc0[nf] = mfma16(pf0, vf, oacc0[nf]);
                oacc1[nf] = mfma16(pf1, vf, oacc1[nf]);
            }
        }
        __builtin_amdgcn_s_setprio(0);
    }

    // final row-sum reductions, normalize, write O bf16 in place
    #pragma unroll
    for (int r = 0; r < 4; ++r) {
        float l = l0[r];
        l += __shfl_xor(l, 1, 16);
        l += __shfl_xor(l, 2, 16);
        l += __shfl_xor(l, 4, 16);
        l += __shfl_xor(l, 8, 16);
        const float inv = 1.f / l;
        #pragma unroll
        for (int nf = 0; nf < 4; ++nf)
            qptr[(size_t)(w * 32 + g * 4 + r) * QKVLD + nf * 16 + lrow] =
                f2bf(oacc0[nf][r] * inv);
    }
    #pragma unroll
    for (int r = 0; r < 4; ++r) {
        float l = l1[r];
        l += __shfl_xor(l, 1, 16);
        l += __shfl_xor(l, 2, 16);
        l += __shfl_xor(l, 4, 16);
        l += __shfl_xor(l, 8, 16);
        const float inv = 1.f / l;
        #pragma unroll
        for (int nf = 0; nf < 4; ++nf)
            qptr[(size_t)(w * 32 + 16 + g * 4 + r) * QKVLD + nf * 16 + lrow] =
                f2bf(oacc1[nf][r] * inv);
    }
}

// ---------------------------------------------------------------------------
// LayerNorm rows of 512; one wave per row. WF32: fp32 out; WB16: bf16 out.
// ---------------------------------------------------------------------------
template<bool WF32, bool WB16>
__global__ __launch_bounds__(256)
void ln_kernel(const float* __restrict__ in, const float* __restrict__ gg,
               const float* __restrict__ bb, float* __restrict__ outf,
               unsigned short* __restrict__ outb)
{
    const int row = blockIdx.x * 4 + (threadIdx.x >> 6);
    const int lane = threadIdx.x & 63;
    const float* p = in + (size_t)row * D_MODEL;

    const float4 a = *(const float4*)(p + lane * 4);
    const float4 c = *(const float4*)(p + 256 + lane * 4);
    float sum = a.x + a.y + a.z + a.w + c.x + c.y + c.z + c.w;
    float sq  = a.x*a.x + a.y*a.y + a.z*a.z + a.w*a.w
              + c.x*c.x + c.y*c.y + c.z*c.z + c.w*c.w;
    #pragma unroll
    for (int msk = 1; msk < 64; msk <<= 1) {
        sum += __shfl_xor(sum, msk, 64);
        sq  += __shfl_xor(sq,  msk, 64);
    }
    const float mean = sum * (1.f / 512.f);
    const float var  = sq * (1.f / 512.f) - mean * mean;
    const float rs   = rsqrtf(var + 1e-5f);

    const float4 g0 = *(const float4*)(gg + lane * 4);
    const float4 g1 = *(const float4*)(gg + 256 + lane * 4);
    const float4 b0 = *(const float4*)(bb + lane * 4);
    const float4 b1 = *(const float4*)(bb + 256 + lane * 4);

    float4 o0, o1;
    o0.x = (a.x - mean) * rs * g0.x + b0.x;
    o0.y = (a.y - mean) * rs * g0.y + b0.y;
    o0.z = (a.z - mean) * rs * g0.z + b0.z;
    o0.w = (a.w - mean) * rs * g0.w + b0.w;
    o1.x = (c.x - mean) * rs * g1.x + b1.x;
    o1.y = (c.y - mean) * rs * g1.y + b1.y;
    o1.z = (c.z - mean) * rs * g1.z + b1.z;
    o1.w = (c.w - mean) * rs * g1.w + b1.w;
    if constexpr (WF32) {
        *(float4*)(outf + (size_t)row * D_MODEL + lane * 4) = o0;
        *(float4*)(outf + (size_t)row * D_MODEL + 256 + lane * 4) = o1;
    }
    if constexpr (WB16) {
        uint2 pa, pb;
        pa.x = cvtpk(o0.x, o0.y);
        pa.y = cvtpk(o0.z, o0.w);
        pb.x = cvtpk(o1.x, o1.y);
        pb.y = cvtpk(o1.z, o1.w);
        *(uint2*)(outb + (size_t)row * D_MODEL + lane * 4) = pa;
        *(uint2*)(outb + (size_t)row * D_MODEL + 256 + lane * 4) = pb;
    }
}

// ---------------------------------------------------------------------------
// fp32 -> bf16 cast, 8 elems/thread
// ---------------------------------------------------------------------------
__global__ __launch_bounds__(256)
void cast_bf16(const float* __restrict__ in, unsigned short* __restrict__ out)
{
    const size_t i = ((size_t)blockIdx.x * 256 + threadIdx.x) * 8;
    const float4 a = *(const float4*)(in + i);
    const float4 b = *(const float4*)(in + i + 4);
    uint4 o;
    o.x = cvtpk(a.x, a.y);
    o.y = cvtpk(a.z, a.w);
    o.z = cvtpk(b.x, b.y);
    o.w = cvtpk(b.z, b.w);
    *(uint4*)(out + i) = o;
}

// ---------------------------------------------------------------------------
// Weight packing: per-head q/k/v weights -> rows 0..511 / 512..1023 /
// 1024..1535 of Wqkv[1536][512] bf16. q scaled by 0.125*log2e (exp2 softmax).
// ---------------------------------------------------------------------------
__global__ __launch_bounds__(256)
void pack_qkv(const float* __restrict__ wq, const float* __restrict__ wk,
              const float* __restrict__ wv, unsigned short* __restrict__ Wqkv)
{
    const int idx = blockIdx.x * 256 + threadIdx.x;   // n*512 + d, n in 0..511
    const int n = idx >> 9, d = idx & 511;
    const int h = n >> 6, c = n & 63;
    const size_t src = ((size_t)h * 512 + d) * 64 + c;
    Wqkv[idx]                 = f2bf(wq[src] * 0.18033688f);  // 0.125 * log2(e)
    Wqkv[idx + 512 * 512]     = f2bf(wk[src]);
    Wqkv[idx + 2 * 512 * 512] = f2bf(wv[src]);
}

// LDS-tiled transpose-cast: in fp32 [K][N] -> out bf16 [N][K], 32x32 tiles,
// coalesced reads and writes.
__global__ __launch_bounds__(256)
void pack_t(const float* __restrict__ in, unsigned short* __restrict__ out,
            int K, int N)
{
    __shared__ float t[32][33];
    const int kb = blockIdx.x << 5, nb = blockIdx.y << 5;
    const int c = threadIdx.x & 31, r0 = threadIdx.x >> 5;   // 8 row-groups
    #pragma unroll
    for (int j = 0; j < 32; j += 8)
        t[r0 + j][c] = in[(size_t)(kb + r0 + j) * N + nb + c];
    __syncthreads();
    #pragma unroll
    for (int j = 0; j < 32; j += 8)
        out[(size_t)(nb + r0 + j) * K + kb + c] = f2bf(t[c][r0 + j]);
}

// ---------------------------------------------------------------------------
extern "C" void kernel_launch(void* const* d_in, const int* in_sizes, int n_in,
                              void* d_out, int out_size, void* d_ws, size_t ws_size,
                              hipStream_t stream)
{
    (void)in_sizes; (void)n_in; (void)out_size;

    const float* x    = (const float*)d_in[0];
    const float* wq   = (const float*)d_in[1];
    const float* wk   = (const float*)d_in[2];
    const float* wv   = (const float*)d_in[3];
    const float* wo   = (const float*)d_in[4];
    const float* w1   = (const float*)d_in[5];
    const float* b1   = (const float*)d_in[6];
    const float* w2   = (const float*)d_in[7];
    const float* b2   = (const float*)d_in[8];
    const float* ln1g = (const float*)d_in[9];
    const float* ln1b = (const float*)d_in[10];
    const float* ln2g = (const float*)d_in[11];
    const float* ln2b = (const float*)d_in[12];
    float* out = (float*)d_out;

    // ---- workspace layout (bytes), fixed part ~90.2 MB ----
    const size_t QKV_BYTES = (size_t)MROWS * QKVLD * 2;      // 50.33 MB
    const size_t Y_BYTES   = (size_t)MROWS * D_MODEL * 4;    // 33.55 MB
    unsigned char* base = (unsigned char*)d_ws;
    unsigned short* qkv  = (unsigned short*)(base);
    float*          y    = (float*)(base + QKV_BYTES);
    unsigned short* Wqkv = (unsigned short*)(base + QKV_BYTES + Y_BYTES);
    unsigned short* wo_t = Wqkv + 3 * 512 * 512;
    unsigned short* w1_t = wo_t + 512 * 512;
    unsigned short* w2_t = w1_t + 2048 * 512;
    unsigned short* hid  = w2_t + 2048 * 512;

    const size_t hid_off = (size_t)((unsigned char*)hid - base);
    const size_t avail = (ws_size > hid_off) ? (ws_size - hid_off) : 0;
    int chunk = (int)(avail / ((size_t)DFF * 2));
    chunk &= ~127;
    if (chunk > MROWS) chunk = MROWS;
    if (chunk < 128)   chunk = 128;

    float* y2 = (float*)qkv;                       // qkv dead after WO GEMM
    // d_out doubles as scratch: xb (bf16 x) until LN1, then x1b (bf16 x1).
    unsigned short* xb  = (unsigned short*)d_out;
    unsigned short* x1b = (unsigned short*)d_out;

    // ---- weight packing + x cast ----
    pack_qkv<<<1024, 256, 0, stream>>>(wq, wk, wv, Wqkv);
    pack_t<<<dim3(16, 16), 256, 0, stream>>>(wo, wo_t, 512, 512);
    pack_t<<<dim3(16, 64), 256, 0, stream>>>(w1, w1_t, 512, 2048);
    pack_t<<<dim3(64, 16), 256, 0, stream>>>(w2, w2_t, 2048, 512);
    cast_bf16<<<(MROWS * D_MODEL) / (256 * 8), 256, 0, stream>>>(x, xb);

    const dim3 blk(256);

    // 1) fused q|k|v projection: xb[M][512] @ Wqkv^T -> qkv[M][1536]  (NF=8)
    mfma_gemm<8, false, false, 0, false>
        <<<dim3(6, MROWS / 128), blk, 0, stream>>>(xb, Wqkv, nullptr, nullptr,
                                                   qkv, 512, 512, QKVLD);

    // 2) flash attention (O bf16 in place over q section), XCD-swizzled grid
    mfma_attn<<<dim3(512), dim3(512), 0, stream>>>(qkv);

    // 3) y = O @ wo + x   (fp32 out, fp32 residual)
    mfma_gemm<4, false, false, 1, true>
        <<<dim3(4, MROWS / 128), blk, 0, stream>>>(qkv, wo_t, nullptr, x, y,
                                                   512, QKVLD, 512);

    // 4) x1 = LN1(y): bf16 only into d_out (FFN2 residual reads bf16)
    ln_kernel<false, true><<<MROWS / 4, blk, 0, stream>>>(y, ln1g, ln1b,
                                                          nullptr, x1b);

    // 5+6) FFN, chunked over rows (chunk multiple of 128)
    for (int r0 = 0; r0 < MROWS; r0 += chunk) {
        const int rows = (r0 + chunk <= MROWS) ? chunk : (MROWS - r0);
        mfma_gemm<8, true, true, 0, false>
            <<<dim3(8, rows / 128), blk, 0, stream>>>(
                x1b + (size_t)r0 * D_MODEL, w1_t, b1, nullptr, hid,
                512, 512, DFF);
        mfma_gemm<4, true, false, 2, true>
            <<<dim3(4, rows / 128), blk, 0, stream>>>(
                hid, w2_t, b2, x1b + (size_t)r0 * D_MODEL,
                y2 + (size_t)r0 * D_MODEL, DFF, DFF, 512);
    }

    // 7) out = LN2(y2)
    ln_kernel<true, false><<<MROWS / 4, blk, 0, stream>>>(y2, ln2g, ln2b,
                                                          out, nullptr);
}

// Round 10
// 297.347 us; speedup vs baseline: 1.4940x; 1.4940x over previous
//
#include <hip/hip_runtime.h>
#include <hip/hip_bf16.h>
#include <math.h>

// ---------------------------------------------------------------------------
// EncoderLayer, bf16-MFMA mixed precision for MI355X (gfx950).
// B=8, S=2048, D=512, H=8, DK=64, DFF=2048, M=16384.
// All GEMMs + attention matmuls: mfma_f32_16x16x32_bf16 (fp32 accumulate).
// Softmax (exp2 domain), LayerNorm, residuals, bias: fp32.
// Round-10: REVERT round-9's two regressions (attn K-direct-to-reg: 8x L2
// traffic + barrier-drained loads; NF=8 GEMM: accumulator register bloat).
// Attention restored to the round-8 best (K in LDS, 106us, MfmaUtil 28%).
// KEPT from round 9: LDS-tiled pack_t, LN1 bf16-only out, FFN2 bf16 residual.
// ---------------------------------------------------------------------------

#define D_MODEL 512
#define NHEAD   8
#define DKH     64
#define SEQ     2048
#define BATCH   8
#define DFF     2048
#define MROWS   (BATCH * SEQ)          // 16384
#define QKVLD   1536                   // fused q|k|v row stride

typedef __bf16 bf16x8 __attribute__((ext_vector_type(8)));
typedef float  f32x4  __attribute__((ext_vector_type(4)));

__device__ __forceinline__ unsigned short f2bf(float f) {
    union { float f; unsigned u; } v; v.f = f;
    return (unsigned short)((v.u + 0x7FFFu + ((v.u >> 16) & 1u)) >> 16);
}

__device__ __forceinline__ float bf2f(unsigned short u) {
    union { unsigned u; float f; } v; v.u = (unsigned)u << 16;
    return v.f;
}

__device__ __forceinline__ unsigned cvtpk(float a, float b) {   // bf16(a)|bf16(b)<<16, RNE
    unsigned r;
    asm("v_cvt_pk_bf16_f32 %0, %1, %2" : "=v"(r) : "v"(a), "v"(b));
    return r;
}

__device__ __forceinline__ float fexp2(float x) {   // raw v_exp_f32 (2^x)
    float r; asm("v_exp_f32 %0, %1" : "=v"(r) : "v"(x)); return r;
}

__device__ __forceinline__ f32x4 mfma16(bf16x8 a, bf16x8 b, f32x4 c) {
    return __builtin_amdgcn_mfma_f32_16x16x32_bf16(a, b, c, 0, 0, 0);
}

// async global -> LDS, 16 B per lane; lds base must be wave-uniform
__device__ __forceinline__ void gld_lds16(const unsigned short* g, unsigned short* l) {
    __builtin_amdgcn_global_load_lds(
        (const __attribute__((address_space(1))) unsigned int*)g,
        (__attribute__((address_space(3))) unsigned int*)l, 16, 0, 0);
}

// ---------------------------------------------------------------------------
// bf16 MFMA GEMM: C[M,N] = A[M,K] * Bt[N,K]^T  (+bias, +relu, +residual)
// 128x128 tile, BK=32, 256 threads = 4 waves, each wave a 64x64 quadrant
// (4x4 fragments of 16x16x32). Double-buffered global_load_lds staging
// (issue next tile before MFMAs of current; one barrier per K-step).
// RESMODE: 0 none, 1 fp32, 2 bf16.
// ---------------------------------------------------------------------------
template<bool BIAS, bool RELU, int RESMODE, bool OUTF32>
__global__ __launch_bounds__(256)
void mfma_gemm(const unsigned short* __restrict__ Av,
               const unsigned short* __restrict__ Bt,
               const float* __restrict__ bias, const void* __restrict__ resv,
               void* __restrict__ Cv, int Kdim, int lda, int ldc)
{
    __shared__ unsigned short As[2][128][32];
    __shared__ unsigned short Bs[2][128][32];

    const int tid  = threadIdx.x;
    const int lane = tid & 63;
    const int w    = tid >> 6;
    const int mq   = (w >> 1) << 6;    // wave quadrant row
    const int nq   = (w & 1) << 6;     // wave quadrant col
    const int lrow = lane & 15;
    const int g    = lane >> 4;
    const int lk   = g << 3;           // k offset of this lane's 8 elems

    const int row0 = blockIdx.y << 7;
    const int col0 = blockIdx.x << 7;

    const int c0   = w << 5;
    const int srow = lane >> 2;
    const int scol = (lane & 3) << 3;
    const size_t aoff = (size_t)(row0 + c0 + srow) * lda  + scol;
    const size_t boff = (size_t)(col0 + c0 + srow) * Kdim + scol;

    auto stage = [&](int buf, int kt) {
        gld_lds16(Av + aoff + kt,                        &As[buf][c0     ][0]);
        gld_lds16(Av + aoff + (size_t)16 * lda  + kt,    &As[buf][c0 + 16][0]);
        gld_lds16(Bt + boff + kt,                        &Bs[buf][c0     ][0]);
        gld_lds16(Bt + boff + (size_t)16 * Kdim + kt,    &Bs[buf][c0 + 16][0]);
    };

    const f32x4 zero = {0.f, 0.f, 0.f, 0.f};
    f32x4 acc[4][4];
    #pragma unroll
    for (int i = 0; i < 4; ++i)
        #pragma unroll
        for (int j = 0; j < 4; ++j) acc[i][j] = zero;

    stage(0, 0);
    __syncthreads();           // drains vmcnt -> buf0 visible

    int cur = 0;
    for (int kt = 0; kt < Kdim; kt += 32) {
        if (kt + 32 < Kdim) stage(cur ^ 1, kt + 32);   // in flight over compute

        bf16x8 af[4], bfv[4];
        #pragma unroll
        for (int mf = 0; mf < 4; ++mf)
            af[mf] = *(const bf16x8*)&As[cur][mq + mf * 16 + lrow][lk];
        #pragma unroll
        for (int nf = 0; nf < 4; ++nf)
            bfv[nf] = *(const bf16x8*)&Bs[cur][nq + nf * 16 + lrow][lk];
        #pragma unroll
        for (int mf = 0; mf < 4; ++mf)
            #pragma unroll
            for (int nf = 0; nf < 4; ++nf)
                acc[mf][nf] = mfma16(af[mf], bfv[nf], acc[mf][nf]);

        __syncthreads();       // drains vmcnt (next buf ready) + read fence
        cur ^= 1;
    }

    // epilogue: C/D layout col = lane&15, row = 4*(lane>>4)+reg
    const int orow = row0 + mq + g * 4;
    const int ocol = col0 + nq + lrow;
    #pragma unroll
    for (int mf = 0; mf < 4; ++mf) {
        #pragma unroll
        for (int nf = 0; nf < 4; ++nf) {
            const int cc = ocol + nf * 16;
            float bv = 0.f;
            if constexpr (BIAS) bv = bias[cc];
            float v[4];
            #pragma unroll
            for (int r = 0; r < 4; ++r) {
                const int rr = orow + mf * 16 + r;
                v[r] = acc[mf][nf][r];
                if constexpr (BIAS) v[r] += bv;
                if constexpr (RELU) v[r] = fmaxf(v[r], 0.f);
                if constexpr (RESMODE == 1)
                    v[r] += ((const float*)resv)[(size_t)rr * ldc + cc];
                if constexpr (RESMODE == 2)
                    v[r] += bf2f(((const unsigned short*)resv)[(size_t)rr * ldc + cc]);
                if constexpr (OUTF32) ((float*)Cv)[(size_t)rr * ldc + cc] = v[r];
            }
            if constexpr (!OUTF32) {
                const unsigned u01 = cvtpk(v[0], v[1]);
                const unsigned u23 = cvtpk(v[2], v[3]);
                unsigned short* cp = (unsigned short*)Cv + (size_t)(orow + mf * 16) * ldc + cc;
                cp[0]                 = (unsigned short)u01;
                cp[(size_t)ldc]       = (unsigned short)(u01 >> 16);
                cp[(size_t)ldc * 2]   = (unsigned short)u23;
                cp[(size_t)ldc * 3]   = (unsigned short)(u23 >> 16);
            }
        }
    }
}

// ---------------------------------------------------------------------------
// Flash attention (round-8 best): 8 waves x 32 Q-rows = 256 Q-rows/block,
// KV tiles of 64, K/V register prefetch into LDS. Softmax exp2-domain,
// defer-max, lazy sum. P in permuted-kv layout (c = 4*lrow + nf) so stores
// are ds_write_b64; V transposed into the same permuted columns.
// Grid 512 blocks, XCD-swizzled (8 bh-groups per XCD).
// ---------------------------------------------------------------------------
__device__ __forceinline__ void softmax_store(
    f32x4* sacc, float* mrun, float* lpart, f32x4* oacc,
    unsigned short (*Ps)[76], int rowbase, int g, int lrow)
{
    float pmax[4];
    bool need = false;
    #pragma unroll
    for (int r = 0; r < 4; ++r) {
        pmax[r] = fmaxf(fmaxf(sacc[0][r], sacc[1][r]),
                        fmaxf(sacc[2][r], sacc[3][r]));
        need |= (pmax[r] > mrun[r] + 8.f);
    }
    if (__any(need)) {   // rare after first tile: full max-reduce + rescale
        #pragma unroll
        for (int r = 0; r < 4; ++r) {
            float mt = pmax[r];
            mt = fmaxf(mt, __shfl_xor(mt, 1, 16));
            mt = fmaxf(mt, __shfl_xor(mt, 2, 16));
            mt = fmaxf(mt, __shfl_xor(mt, 4, 16));
            mt = fmaxf(mt, __shfl_xor(mt, 8, 16));
            const float mnew = fmaxf(mrun[r], mt);
            const float alpha = fexp2(mrun[r] - mnew);  // first tile: 0
            mrun[r] = mnew;
            lpart[r] *= alpha;
            #pragma unroll
            for (int nf = 0; nf < 4; ++nf) oacc[nf][r] *= alpha;
        }
    }
    #pragma unroll
    for (int r = 0; r < 4; ++r) {
        const float p0 = fexp2(sacc[0][r] - mrun[r]);
        const float p1 = fexp2(sacc[1][r] - mrun[r]);
        const float p2 = fexp2(sacc[2][r] - mrun[r]);
        const float p3 = fexp2(sacc[3][r] - mrun[r]);
        lpart[r] += (p0 + p1) + (p2 + p3);
        uint2 u;
        u.x = cvtpk(p0, p1);     // cols 4*lrow, 4*lrow+1  (nf=0,1)
        u.y = cvtpk(p2, p3);     // cols 4*lrow+2, +3      (nf=2,3)
        *(uint2*)&Ps[rowbase + g * 4 + r][4 * lrow] = u;
    }
}

__global__ __launch_bounds__(512, 4)
void mfma_attn(unsigned short* __restrict__ qkv)
{
    __shared__ unsigned short Ks[64][72];    // K tile [kv][dk]
    __shared__ unsigned short Vt[64][72];    // V' transposed [dk][c(kv)]
    __shared__ unsigned short Ps[256][76];   // P' [qrow][c(kv)]

    const int tid  = threadIdx.x;
    const int lane = tid & 63;
    const int w    = tid >> 6;
    const int lrow = lane & 15;
    const int g    = lane >> 4;
    const int lk   = g << 3;

    // XCD swizzle: 512 blocks = 8 xcd x 8 bh-groups x 8 q-tiles
    const int bid  = blockIdx.x;
    const int idx  = bid >> 3;
    const int bh   = (bid & 7) * 8 + (idx & 7);
    const int b  = bh >> 3, h = bh & 7;
    const int s0 = (idx >> 3) << 8;              // q-tile start (256 rows)

    unsigned short* qptr = qkv + ((size_t)(b * SEQ + s0)) * QKVLD + h * DKH;
    const unsigned short* kbase = qkv + ((size_t)(b * SEQ)) * QKVLD + 512 + h * DKH;
    const unsigned short* vbase = qkv + ((size_t)(b * SEQ)) * QKVLD + 1024 + h * DKH;

    // Q fragments for both 16-row sub-tiles (pre-scaled 0.125*log2e via pack)
    bf16x8 qf[2][2];
    #pragma unroll
    for (int sub = 0; sub < 2; ++sub) {
        const unsigned short* qp = qptr + (size_t)(w * 32 + sub * 16 + lrow) * QKVLD;
        qf[sub][0] = *(const bf16x8*)(qp + lk);
        qf[sub][1] = *(const bf16x8*)(qp + 32 + lk);
    }

    // staging indices
    const int kr = tid >> 3, kc = (tid & 7) << 3;   // K: 64 rows x 64 cols
    const int vr = tid & 63, vc = (tid >> 6) << 3;  // V: row=vr, 8-col slab
    const int cvr = ((vr & 15) << 2) | (vr >> 4);   // permuted col of kv=vr

    uint4 kreg, vreg;
    auto loadKV = [&](int t0) {
        kreg = *(const uint4*)(kbase + (size_t)(t0 + kr) * QKVLD + kc);
        vreg = *(const uint4*)(vbase + (size_t)(t0 + vr) * QKVLD + vc);
    };
    loadKV(0);

    const f32x4 zero = {0.f, 0.f, 0.f, 0.f};
    f32x4 oacc0[4], oacc1[4];
    float m0[4], l0[4], m1[4], l1[4];
    #pragma unroll
    for (int i = 0; i < 4; ++i) {
        oacc0[i] = zero; oacc1[i] = zero;
        m0[i] = -INFINITY; m1[i] = -INFINITY; l0[i] = 0.f; l1[i] = 0.f;
    }

    for (int t0 = 0; t0 < SEQ; t0 += 64) {
        __syncthreads();   // previous tile's LDS reads complete
        *(uint4*)&Ks[kr][kc] = kreg;
        {
            const unsigned short* vu = (const unsigned short*)&vreg;
            #pragma unroll
            for (int j = 0; j < 8; ++j) Vt[vc + j][cvr] = vu[j];
        }
        __syncthreads();

        if (t0 + 64 < SEQ) loadKV(t0 + 64);   // prefetch, in flight over compute

        // S = Q K^T for both sub-tiles; kf shared (read once, 2 MFMAs)
        f32x4 s0a[4], s1a[4];
        #pragma unroll
        for (int nf = 0; nf < 4; ++nf) { s0a[nf] = zero; s1a[nf] = zero; }
        __builtin_amdgcn_s_setprio(1);
        #pragma unroll
        for (int kk = 0; kk < 2; ++kk) {
            #pragma unroll
            for (int nf = 0; nf < 4; ++nf) {
                const bf16x8 kf = *(const bf16x8*)&Ks[nf * 16 + lrow][kk * 32 + lk];
                s0a[nf] = mfma16(qf[0][kk], kf, s0a[nf]);
                s1a[nf] = mfma16(qf[1][kk], kf, s1a[nf]);
            }
        }
        __builtin_amdgcn_s_setprio(0);

        softmax_store(s0a, m0, l0, oacc0, Ps, w * 32,      g, lrow);
        softmax_store(s1a, m1, l1, oacc1, Ps, w * 32 + 16, g, lrow);

        // O += P' V'   (vf shared across sub-tiles)
        __builtin_amdgcn_s_setprio(1);
        #pragma unroll
        for (int kk = 0; kk < 2; ++kk) {
            const bf16x8 pf0 = *(const bf16x8*)&Ps[w * 32 + lrow][kk * 32 + lk];
            const bf16x8 pf1 = *(const bf16x8*)&Ps[w * 32 + 16 + lrow][kk * 32 + lk];
            #pragma unroll
            for (int nf = 0; nf < 4; ++nf) {
                const bf16x8 vf = *(const bf16x8*)&Vt[nf * 16 + lrow][kk * 32 + lk];
                oacc0[nf] = mfma16(pf0, vf, oacc0[nf]);
                oacc1[nf] = mfma16(pf1, vf, oacc1[nf]);
            }
        }
        __builtin_amdgcn_s_setprio(0);
    }

    // final row-sum reductions, normalize, write O bf16 in place
    #pragma unroll
    for (int r = 0; r < 4; ++r) {
        float l = l0[r];
        l += __shfl_xor(l, 1, 16);
        l += __shfl_xor(l, 2, 16);
        l += __shfl_xor(l, 4, 16);
        l += __shfl_xor(l, 8, 16);
        const float inv = 1.f / l;
        #pragma unroll
        for (int nf = 0; nf < 4; ++nf)
            qptr[(size_t)(w * 32 + g * 4 + r) * QKVLD + nf * 16 + lrow] =
                f2bf(oacc0[nf][r] * inv);
    }
    #pragma unroll
    for (int r = 0; r < 4; ++r) {
        float l = l1[r];
        l += __shfl_xor(l, 1, 16);
        l += __shfl_xor(l, 2, 16);
        l += __shfl_xor(l, 4, 16);
        l += __shfl_xor(l, 8, 16);
        const float inv = 1.f / l;
        #pragma unroll
        for (int nf = 0; nf < 4; ++nf)
            qptr[(size_t)(w * 32 + 16 + g * 4 + r) * QKVLD + nf * 16 + lrow] =
                f2bf(oacc1[nf][r] * inv);
    }
}

// ---------------------------------------------------------------------------
// LayerNorm rows of 512; one wave per row. WF32: fp32 out; WB16: bf16 out.
// ---------------------------------------------------------------------------
template<bool WF32, bool WB16>
__global__ __launch_bounds__(256)
void ln_kernel(const float* __restrict__ in, const float* __restrict__ gg,
               const float* __restrict__ bb, float* __restrict__ outf,
               unsigned short* __restrict__ outb)
{
    const int row = blockIdx.x * 4 + (threadIdx.x >> 6);
    const int lane = threadIdx.x & 63;
    const float* p = in + (size_t)row * D_MODEL;

    const float4 a = *(const float4*)(p + lane * 4);
    const float4 c = *(const float4*)(p + 256 + lane * 4);
    float sum = a.x + a.y + a.z + a.w + c.x + c.y + c.z + c.w;
    float sq  = a.x*a.x + a.y*a.y + a.z*a.z + a.w*a.w
              + c.x*c.x + c.y*c.y + c.z*c.z + c.w*c.w;
    #pragma unroll
    for (int msk = 1; msk < 64; msk <<= 1) {
        sum += __shfl_xor(sum, msk, 64);
        sq  += __shfl_xor(sq,  msk, 64);
    }
    const float mean = sum * (1.f / 512.f);
    const float var  = sq * (1.f / 512.f) - mean * mean;
    const float rs   = rsqrtf(var + 1e-5f);

    const float4 g0 = *(const float4*)(gg + lane * 4);
    const float4 g1 = *(const float4*)(gg + 256 + lane * 4);
    const float4 b0 = *(const float4*)(bb + lane * 4);
    const float4 b1 = *(const float4*)(bb + 256 + lane * 4);

    float4 o0, o1;
    o0.x = (a.x - mean) * rs * g0.x + b0.x;
    o0.y = (a.y - mean) * rs * g0.y + b0.y;
    o0.z = (a.z - mean) * rs * g0.z + b0.z;
    o0.w = (a.w - mean) * rs * g0.w + b0.w;
    o1.x = (c.x - mean) * rs * g1.x + b1.x;
    o1.y = (c.y - mean) * rs * g1.y + b1.y;
    o1.z = (c.z - mean) * rs * g1.z + b1.z;
    o1.w = (c.w - mean) * rs * g1.w + b1.w;
    if constexpr (WF32) {
        *(float4*)(outf + (size_t)row * D_MODEL + lane * 4) = o0;
        *(float4*)(outf + (size_t)row * D_MODEL + 256 + lane * 4) = o1;
    }
    if constexpr (WB16) {
        uint2 pa, pb;
        pa.x = cvtpk(o0.x, o0.y);
        pa.y = cvtpk(o0.z, o0.w);
        pb.x = cvtpk(o1.x, o1.y);
        pb.y = cvtpk(o1.z, o1.w);
        *(uint2*)(outb + (size_t)row * D_MODEL + lane * 4) = pa;
        *(uint2*)(outb + (size_t)row * D_MODEL + 256 + lane * 4) = pb;
    }
}

// ---------------------------------------------------------------------------
// fp32 -> bf16 cast, 8 elems/thread
// ---------------------------------------------------------------------------
__global__ __launch_bounds__(256)
void cast_bf16(const float* __restrict__ in, unsigned short* __restrict__ out)
{
    const size_t i = ((size_t)blockIdx.x * 256 + threadIdx.x) * 8;
    const float4 a = *(const float4*)(in + i);
    const float4 b = *(const float4*)(in + i + 4);
    uint4 o;
    o.x = cvtpk(a.x, a.y);
    o.y = cvtpk(a.z, a.w);
    o.z = cvtpk(b.x, b.y);
    o.w = cvtpk(b.z, b.w);
    *(uint4*)(out + i) = o;
}

// ---------------------------------------------------------------------------
// Weight packing: per-head q/k/v weights -> rows 0..511 / 512..1023 /
// 1024..1535 of Wqkv[1536][512] bf16. q scaled by 0.125*log2e (exp2 softmax).
// ---------------------------------------------------------------------------
__global__ __launch_bounds__(256)
void pack_qkv(const float* __restrict__ wq, const float* __restrict__ wk,
              const float* __restrict__ wv, unsigned short* __restrict__ Wqkv)
{
    const int idx = blockIdx.x * 256 + threadIdx.x;   // n*512 + d, n in 0..511
    const int n = idx >> 9, d = idx & 511;
    const int h = n >> 6, c = n & 63;
    const size_t src = ((size_t)h * 512 + d) * 64 + c;
    Wqkv[idx]                 = f2bf(wq[src] * 0.18033688f);  // 0.125 * log2(e)
    Wqkv[idx + 512 * 512]     = f2bf(wk[src]);
    Wqkv[idx + 2 * 512 * 512] = f2bf(wv[src]);
}

// LDS-tiled transpose-cast: in fp32 [K][N] -> out bf16 [N][K], 32x32 tiles,
// coalesced reads and writes.
__global__ __launch_bounds__(256)
void pack_t(const float* __restrict__ in, unsigned short* __restrict__ out,
            int K, int N)
{
    __shared__ float t[32][33];
    const int kb = blockIdx.x << 5, nb = blockIdx.y << 5;
    const int c = threadIdx.x & 31, r0 = threadIdx.x >> 5;   // 8 row-groups
    #pragma unroll
    for (int j = 0; j < 32; j += 8)
        t[r0 + j][c] = in[(size_t)(kb + r0 + j) * N + nb + c];
    __syncthreads();
    #pragma unroll
    for (int j = 0; j < 32; j += 8)
        out[(size_t)(nb + r0 + j) * K + kb + c] = f2bf(t[c][r0 + j]);
}

// ---------------------------------------------------------------------------
extern "C" void kernel_launch(void* const* d_in, const int* in_sizes, int n_in,
                              void* d_out, int out_size, void* d_ws, size_t ws_size,
                              hipStream_t stream)
{
    (void)in_sizes; (void)n_in; (void)out_size;

    const float* x    = (const float*)d_in[0];
    const float* wq   = (const float*)d_in[1];
    const float* wk   = (const float*)d_in[2];
    const float* wv   = (const float*)d_in[3];
    const float* wo   = (const float*)d_in[4];
    const float* w1   = (const float*)d_in[5];
    const float* b1   = (const float*)d_in[6];
    const float* w2   = (const float*)d_in[7];
    const float* b2   = (const float*)d_in[8];
    const float* ln1g = (const float*)d_in[9];
    const float* ln1b = (const float*)d_in[10];
    const float* ln2g = (const float*)d_in[11];
    const float* ln2b = (const float*)d_in[12];
    float* out = (float*)d_out;

    // ---- workspace layout (bytes), fixed part ~90.2 MB ----
    const size_t QKV_BYTES = (size_t)MROWS * QKVLD * 2;      // 50.33 MB
    const size_t Y_BYTES   = (size_t)MROWS * D_MODEL * 4;    // 33.55 MB
    unsigned char* base = (unsigned char*)d_ws;
    unsigned short* qkv  = (unsigned short*)(base);
    float*          y    = (float*)(base + QKV_BYTES);
    unsigned short* Wqkv = (unsigned short*)(base + QKV_BYTES + Y_BYTES);
    unsigned short* wo_t = Wqkv + 3 * 512 * 512;
    unsigned short* w1_t = wo_t + 512 * 512;
    unsigned short* w2_t = w1_t + 2048 * 512;
    unsigned short* hid  = w2_t + 2048 * 512;

    const size_t hid_off = (size_t)((unsigned char*)hid - base);
    const size_t avail = (ws_size > hid_off) ? (ws_size - hid_off) : 0;
    int chunk = (int)(avail / ((size_t)DFF * 2));
    chunk &= ~127;
    if (chunk > MROWS) chunk = MROWS;
    if (chunk < 128)   chunk = 128;

    float* y2 = (float*)qkv;                       // qkv dead after WO GEMM
    // d_out doubles as scratch: xb (bf16 x) until LN1, then x1b (bf16 x1).
    unsigned short* xb  = (unsigned short*)d_out;
    unsigned short* x1b = (unsigned short*)d_out;

    // ---- weight packing + x cast ----
    pack_qkv<<<1024, 256, 0, stream>>>(wq, wk, wv, Wqkv);
    pack_t<<<dim3(16, 16), 256, 0, stream>>>(wo, wo_t, 512, 512);
    pack_t<<<dim3(16, 64), 256, 0, stream>>>(w1, w1_t, 512, 2048);
    pack_t<<<dim3(64, 16), 256, 0, stream>>>(w2, w2_t, 2048, 512);
    cast_bf16<<<(MROWS * D_MODEL) / (256 * 8), 256, 0, stream>>>(x, xb);

    const dim3 blk(256);

    // 1) fused q|k|v projection: xb[M][512] @ Wqkv^T -> qkv[M][1536]
    mfma_gemm<false, false, 0, false>
        <<<dim3(12, MROWS / 128), blk, 0, stream>>>(xb, Wqkv, nullptr, nullptr,
                                                    qkv, 512, 512, QKVLD);

    // 2) flash attention (O bf16 in place over q section), XCD-swizzled grid
    mfma_attn<<<dim3(512), dim3(512), 0, stream>>>(qkv);

    // 3) y = O @ wo + x   (fp32 out, fp32 residual)
    mfma_gemm<false, false, 1, true>
        <<<dim3(4, MROWS / 128), blk, 0, stream>>>(qkv, wo_t, nullptr, x, y,
                                                   512, QKVLD, 512);

    // 4) x1 = LN1(y): bf16 only into d_out (FFN2 residual reads bf16)
    ln_kernel<false, true><<<MROWS / 4, blk, 0, stream>>>(y, ln1g, ln1b,
                                                          nullptr, x1b);

    // 5+6) FFN, chunked over rows (chunk multiple of 128)
    for (int r0 = 0; r0 < MROWS; r0 += chunk) {
        const int rows = (r0 + chunk <= MROWS) ? chunk : (MROWS - r0);
        mfma_gemm<true, true, 0, false>
            <<<dim3(DFF / 128, rows / 128), blk, 0, stream>>>(
                x1b + (size_t)r0 * D_MODEL, w1_t, b1, nullptr, hid,
                512, 512, DFF);
        mfma_gemm<true, false, 2, true>
            <<<dim3(4, rows / 128), blk, 0, stream>>>(
                hid, w2_t, b2, x1b + (size_t)r0 * D_MODEL,
                y2 + (size_t)r0 * D_MODEL, DFF, DFF, 512);
    }

    // 7) out = LN2(y2)
    ln_kernel<true, false><<<MROWS / 4, blk, 0, stream>>>(y2, ln2g, ln2b,
                                                          out, nullptr);
}